// Round 1
// baseline (374.035 us; speedup 1.0000x reference)
//
#include <hip/hip_runtime.h>
#include <hip/hip_bf16.h>

typedef __bf16 bf16_t;
typedef __bf16 bf16x8 __attribute__((ext_vector_type(8)));
typedef float f32x4 __attribute__((ext_vector_type(4)));

#define LOG2E 1.4426950408889634f

__device__ __forceinline__ f32x4 mfma16(bf16x8 a, bf16x8 b, f32x4 c) {
  return __builtin_amdgcn_mfma_f32_16x16x32_bf16(a, b, c, 0, 0, 0);
}

// ---------------------------------------------------------------------------
// Projection GEMM: C[bt, h*64+p] = sum_d A[bt,d] * W[h,d,p]
// A: (4096,1024) f32 row-major.  W: (16,1024,64) f32.  out: bf16 (B,H,T,P).
// Tile 128x128, BK=64, 4 waves, mfma 16x16x32 bf16.
// ---------------------------------------------------------------------------
__global__ __launch_bounds__(256) void proj_gemm_kernel(
    const float* __restrict__ A, const float* __restrict__ W,
    bf16_t* __restrict__ out) {
  __shared__ bf16_t As[128][72];  // [row][k], pad 8 -> 2-way bank alias (free)
  __shared__ bf16_t Bs[128][72];  // [col][k]  (B pre-transposed into LDS)
  const int tid = threadIdx.x;
  const int lane = tid & 63;
  const int wid = tid >> 6;
  const int wm = wid >> 1, wn = wid & 1;
  const int row0 = blockIdx.x * 128;
  const int col0 = blockIdx.y * 128;
  const int lr = lane & 15;
  const int lk = (lane >> 4) * 8;

  f32x4 acc[4][4];
#pragma unroll
  for (int m = 0; m < 4; m++)
#pragma unroll
    for (int n = 0; n < 4; n++) acc[m][n] = {0.f, 0.f, 0.f, 0.f};

  for (int kt = 0; kt < 1024; kt += 64) {
    // stage A (f32 -> bf16): 128 rows x 64 k, 8 elems per thread-chunk
#pragma unroll
    for (int i = 0; i < 4; i++) {
      int c = tid + i * 256;
      int row = c >> 3;
      int k8 = (c & 7) * 8;
      const float* src = A + (size_t)(row0 + row) * 1024 + kt + k8;
      bf16_t* dst = &As[row][k8];
#pragma unroll
      for (int j = 0; j < 8; j++) dst[j] = (bf16_t)src[j];
    }
    // stage B transposed: Bs[col][k] = W[h, k, p], col = h*64+p
#pragma unroll
    for (int i = 0; i < 4; i++) {
      int c = tid + i * 256;
      int col = c & 127;
      int k8 = (c >> 7) * 8;
      int gcol = col0 + col;
      int h = gcol >> 6, p = gcol & 63;
      const float* src = W + (size_t)h * 65536 + (size_t)(kt + k8) * 64 + p;
      bf16_t* dst = &Bs[col][k8];
#pragma unroll
      for (int j = 0; j < 8; j++) dst[j] = (bf16_t)src[j * 64];
    }
    __syncthreads();
#pragma unroll
    for (int kk = 0; kk < 2; kk++) {
      bf16x8 af[4], bfr[4];
#pragma unroll
      for (int m = 0; m < 4; m++)
        af[m] = *(const bf16x8*)&As[wm * 64 + m * 16 + lr][kk * 32 + lk];
#pragma unroll
      for (int n = 0; n < 4; n++)
        bfr[n] = *(const bf16x8*)&Bs[wn * 64 + n * 16 + lr][kk * 32 + lk];
#pragma unroll
      for (int m = 0; m < 4; m++)
#pragma unroll
        for (int n = 0; n < 4; n++)
          acc[m][n] = mfma16(af[m], bfr[n], acc[m][n]);
    }
    __syncthreads();
  }
  const int rb = (lane >> 4) * 4;
#pragma unroll
  for (int m = 0; m < 4; m++) {
#pragma unroll
    for (int n = 0; n < 4; n++) {
      int col = col0 + wn * 64 + n * 16 + lr;
      int h = col >> 6, p = col & 63;
#pragma unroll
      for (int r = 0; r < 4; r++) {
        int row = row0 + wm * 64 + m * 16 + rb + r;
        int b = row >> 11, tt = row & 2047;
        out[(((size_t)(b * 16 + h) * 2048 + tt) * 64) + p] = (bf16_t)acc[m][n][r];
      }
    }
  }
}

// ---------------------------------------------------------------------------
// Dense output GEMM: out[bt, n] = sum_k ctx[bt,k]*W[k,n] + bias[n]
// ctx: (4096,1024) bf16 row-major.  W: (1024,1024) f32 row-major.  out f32.
// ---------------------------------------------------------------------------
__global__ __launch_bounds__(256) void dense_gemm_kernel(
    const bf16_t* __restrict__ A, const float* __restrict__ W,
    const float* __restrict__ bias, float* __restrict__ out) {
  __shared__ bf16_t As[128][72];
  __shared__ bf16_t Bs[128][72];
  const int tid = threadIdx.x;
  const int lane = tid & 63;
  const int wid = tid >> 6;
  const int wm = wid >> 1, wn = wid & 1;
  const int row0 = blockIdx.x * 128;
  const int col0 = blockIdx.y * 128;
  const int lr = lane & 15;
  const int lk = (lane >> 4) * 8;

  f32x4 acc[4][4];
#pragma unroll
  for (int m = 0; m < 4; m++)
#pragma unroll
    for (int n = 0; n < 4; n++) acc[m][n] = {0.f, 0.f, 0.f, 0.f};

  for (int kt = 0; kt < 1024; kt += 64) {
#pragma unroll
    for (int i = 0; i < 4; i++) {
      int c = tid + i * 256;
      int row = c >> 3;
      int k8 = (c & 7) * 8;
      *(uint4*)&As[row][k8] =
          *(const uint4*)(A + (size_t)(row0 + row) * 1024 + kt + k8);
    }
#pragma unroll
    for (int i = 0; i < 4; i++) {
      int c = tid + i * 256;
      int col = c & 127;
      int k8 = (c >> 7) * 8;
      const float* src = W + (size_t)(kt + k8) * 1024 + col0 + col;
      bf16_t* dst = &Bs[col][k8];
#pragma unroll
      for (int j = 0; j < 8; j++) dst[j] = (bf16_t)src[j * 1024];
    }
    __syncthreads();
#pragma unroll
    for (int kk = 0; kk < 2; kk++) {
      bf16x8 af[4], bfr[4];
#pragma unroll
      for (int m = 0; m < 4; m++)
        af[m] = *(const bf16x8*)&As[wm * 64 + m * 16 + lr][kk * 32 + lk];
#pragma unroll
      for (int n = 0; n < 4; n++)
        bfr[n] = *(const bf16x8*)&Bs[wn * 64 + n * 16 + lr][kk * 32 + lk];
#pragma unroll
      for (int m = 0; m < 4; m++)
#pragma unroll
        for (int n = 0; n < 4; n++)
          acc[m][n] = mfma16(af[m], bfr[n], acc[m][n]);
    }
    __syncthreads();
  }
  const int rb = (lane >> 4) * 4;
#pragma unroll
  for (int m = 0; m < 4; m++) {
#pragma unroll
    for (int n = 0; n < 4; n++) {
      int col = col0 + wn * 64 + n * 16 + lr;
      float bv = bias[col];
#pragma unroll
      for (int r = 0; r < 4; r++) {
        int row = row0 + wm * 64 + m * 16 + rb + r;
        out[(size_t)row * 1024 + col] = acc[m][n][r] + bv;
      }
    }
  }
}

// ---------------------------------------------------------------------------
// Flash attention with Shaw relative-position bias.
// q,k,v: bf16 (B,H,T,P) = (2,16,2048,64).  rel: f32 (4095,64). mask: f32 (B,T).
// ctx out: bf16 (BT, H*P) row-major for the dense GEMM.
// One WG = one (b,h) x 64-row tile; 4 waves, each owns 16 rows. BN=64.
// ---------------------------------------------------------------------------
__global__ __launch_bounds__(256) void attn_kernel(
    const bf16_t* __restrict__ qg, const bf16_t* __restrict__ kg,
    const bf16_t* __restrict__ vg, const float* __restrict__ rel,
    const float* __restrict__ mask, bf16_t* __restrict__ ctx) {
  __shared__ bf16_t Kt[64][72];       // [j][p]
  __shared__ bf16_t Vt[64][72];       // [p][j]  (transposed for PV B-operand)
  __shared__ bf16_t Rt[128][72];      // [r'][p]
  __shared__ bf16_t EL[4][16][128];   // per-wave Erel tile (bf16 logits ok)
  __shared__ bf16_t PL[4][16][72];    // per-wave P tile (A-operand for PV)

  const int tid = threadIdx.x;
  const int lane = tid & 63;
  const int w = tid >> 6;
  const int it = blockIdx.x;
  const int h = blockIdx.y;
  const int b = blockIdx.z;
  const int bh = b * 16 + h;
  const int i0 = it * 64;
  const size_t base = (size_t)bh * 2048 * 64;
  const int lr = lane & 15;
  const int lk = (lane >> 4) * 8;
  const int rloc = (lane >> 4) * 4;

  // Q fragments for this wave's 16 rows (full P=64 -> 2 k-steps)
  bf16x8 aq[2];
  {
    int row = i0 + w * 16 + lr;
    const bf16_t* src = qg + base + (size_t)row * 64 + lk;
    aq[0] = *(const bf16x8*)(src);
    aq[1] = *(const bf16x8*)(src + 32);
  }

  float mrow[4], lrow[4];
  f32x4 o[4];
#pragma unroll
  for (int r = 0; r < 4; r++) { mrow[r] = -INFINITY; lrow[r] = 0.f; }
#pragma unroll
  for (int n = 0; n < 4; n++) o[n] = {0.f, 0.f, 0.f, 0.f};

  const float* maskb = mask + (size_t)b * 2048;

  for (int jt = 0; jt < 32; jt++) {
    const int j0 = jt * 64;
    // stage K: [j][p]
#pragma unroll
    for (int i = 0; i < 2; i++) {
      int c = tid + i * 256;
      int row = c >> 3;
      int k8 = (c & 7) * 8;
      *(uint4*)&Kt[row][k8] =
          *(const uint4*)(kg + base + (size_t)(j0 + row) * 64 + k8);
    }
    // stage V transposed: Vt[p][j]
#pragma unroll
    for (int i = 0; i < 2; i++) {
      int c = tid + i * 256;
      int p = c & 63;
      int j8 = (c >> 6) * 8;
      const bf16_t* src = vg + base + (size_t)(j0 + j8) * 64 + p;
      bf16_t* dst = &Vt[p][j8];
#pragma unroll
      for (int jj = 0; jj < 8; jj++) dst[jj] = src[jj * 64];
    }
    // stage rel slice: Rt[r'][p], r' = r - (j0 - i0 + 2047 - 63), clamped
    const int rbase = j0 - i0 + 2047 - 63;
#pragma unroll
    for (int i = 0; i < 4; i++) {
      int c = tid + i * 256;
      int rr = c >> 3;
      int k8 = (c & 7) * 8;
      int rg = rbase + rr;
      rg = rg < 0 ? 0 : (rg > 4094 ? 4094 : rg);
      const float* src = rel + (size_t)rg * 64 + k8;
      bf16_t* dst = &Rt[rr][k8];
#pragma unroll
      for (int j = 0; j < 8; j++) dst[j] = (bf16_t)src[j];
    }
    __syncthreads();

    // S = q k^T  (4 col-frags) and Erel = q R^T (8 col-frags)
    f32x4 sacc[4];
    f32x4 er[8];
#pragma unroll
    for (int n = 0; n < 4; n++) sacc[n] = {0.f, 0.f, 0.f, 0.f};
#pragma unroll
    for (int n = 0; n < 8; n++) er[n] = {0.f, 0.f, 0.f, 0.f};
#pragma unroll
    for (int kk = 0; kk < 2; kk++) {
#pragma unroll
      for (int n = 0; n < 4; n++) {
        bf16x8 bk = *(const bf16x8*)&Kt[n * 16 + lr][kk * 32 + lk];
        sacc[n] = mfma16(aq[kk], bk, sacc[n]);
      }
#pragma unroll
      for (int n = 0; n < 8; n++) {
        bf16x8 br = *(const bf16x8*)&Rt[n * 16 + lr][kk * 32 + lk];
        er[n] = mfma16(aq[kk], br, er[n]);
      }
    }
    // spill Erel to LDS for the diagonal gather
#pragma unroll
    for (int n = 0; n < 8; n++)
#pragma unroll
      for (int r = 0; r < 4; r++)
        EL[w][rloc + r][n * 16 + lr] = (bf16_t)er[n][r];
    __syncthreads();

    // build scaled energies + online softmax
    float stot[4][4];
#pragma unroll
    for (int n = 0; n < 4; n++) {
      int dj = n * 16 + lr;
      float mb = (1.0f - maskb[j0 + dj]) * -1e9f;
#pragma unroll
      for (int r = 0; r < 4; r++) {
        int di = w * 16 + rloc + r;
        int ridx = dj - di + 63;  // in [0,126]
        stot[n][r] = (sacc[n][r] + (float)EL[w][rloc + r][ridx]) * 0.125f + mb;
      }
    }
    float pr[4][4];
#pragma unroll
    for (int r = 0; r < 4; r++) {
      float v4 = fmaxf(fmaxf(stot[0][r], stot[1][r]),
                       fmaxf(stot[2][r], stot[3][r]));
#pragma unroll
      for (int xm = 1; xm < 16; xm <<= 1) v4 = fmaxf(v4, __shfl_xor(v4, xm, 64));
      float mnew = fmaxf(mrow[r], v4);
      float fac = exp2f((mrow[r] - mnew) * LOG2E);
      mrow[r] = mnew;
      float ps = 0.f;
#pragma unroll
      for (int n = 0; n < 4; n++) {
        pr[n][r] = exp2f((stot[n][r] - mnew) * LOG2E);
        ps += pr[n][r];
      }
#pragma unroll
      for (int xm = 1; xm < 16; xm <<= 1) ps += __shfl_xor(ps, xm, 64);
      lrow[r] = lrow[r] * fac + ps;
#pragma unroll
      for (int n = 0; n < 4; n++) o[n][r] *= fac;
    }
    // P tile -> LDS (A-operand layout for PV)
#pragma unroll
    for (int n = 0; n < 4; n++)
#pragma unroll
      for (int r = 0; r < 4; r++)
        PL[w][rloc + r][n * 16 + lr] = (bf16_t)pr[n][r];
    __syncthreads();

    // PV: o += P @ V   (K-dim = 64 keys)
#pragma unroll
    for (int kk = 0; kk < 2; kk++) {
      bf16x8 ap = *(const bf16x8*)&PL[w][lr][kk * 32 + lk];
#pragma unroll
      for (int n = 0; n < 4; n++) {
        bf16x8 bv = *(const bf16x8*)&Vt[n * 16 + lr][kk * 32 + lk];
        o[n] = mfma16(ap, bv, o[n]);
      }
    }
    __syncthreads();
  }

  // write ctx (bt, h*64+p) bf16
#pragma unroll
  for (int n = 0; n < 4; n++) {
    int p = n * 16 + lr;
#pragma unroll
    for (int r = 0; r < 4; r++) {
      int row = i0 + w * 16 + rloc + r;
      int bt = b * 2048 + row;
      ctx[(size_t)bt * 1024 + h * 64 + p] = (bf16_t)(o[n][r] / lrow[r]);
    }
  }
}

// ---------------------------------------------------------------------------
extern "C" void kernel_launch(void* const* d_in, const int* in_sizes, int n_in,
                              void* d_out, int out_size, void* d_ws,
                              size_t ws_size, hipStream_t stream) {
  (void)in_sizes; (void)n_in; (void)out_size; (void)ws_size;
  const float* Q    = (const float*)d_in[0];
  const float* K    = (const float*)d_in[1];
  const float* V    = (const float*)d_in[2];
  const float* mask = (const float*)d_in[3];
  const float* WQ   = (const float*)d_in[4];
  const float* WK   = (const float*)d_in[5];
  const float* WV   = (const float*)d_in[6];
  const float* rel  = (const float*)d_in[7];
  const float* dW   = (const float*)d_in[8];
  const float* db   = (const float*)d_in[9];
  float* out = (float*)d_out;

  const size_t NQKV = (size_t)2 * 16 * 2048 * 64;  // 4,194,304 elems
  bf16_t* qb  = (bf16_t*)d_ws;
  bf16_t* kb  = qb + NQKV;
  bf16_t* vb  = kb + NQKV;
  bf16_t* ctx = vb + NQKV;

  dim3 blk(256);
  dim3 gemm_grid(32, 8);  // 4096/128 x 1024/128
  proj_gemm_kernel<<<gemm_grid, blk, 0, stream>>>(Q, WQ, qb);
  proj_gemm_kernel<<<gemm_grid, blk, 0, stream>>>(K, WK, kb);
  proj_gemm_kernel<<<gemm_grid, blk, 0, stream>>>(V, WV, vb);
  attn_kernel<<<dim3(32, 16, 2), blk, 0, stream>>>(qb, kb, vb, rel, mask, ctx);
  dense_gemm_kernel<<<gemm_grid, blk, 0, stream>>>(ctx, dW, db, out);
}

// Round 2
// 326.844 us; speedup vs baseline: 1.1444x; 1.1444x over previous
//
#include <hip/hip_runtime.h>
#include <hip/hip_bf16.h>

typedef __bf16 bf16_t;
typedef __bf16 bf16x8 __attribute__((ext_vector_type(8)));
typedef float f32x4 __attribute__((ext_vector_type(4)));

#define LOG2E 1.4426950408889634f

__device__ __forceinline__ f32x4 mfma16(bf16x8 a, bf16x8 b, f32x4 c) {
  return __builtin_amdgcn_mfma_f32_16x16x32_bf16(a, b, c, 0, 0, 0);
}

#define GLDS16(gsrc, ldst)                                                     \
  __builtin_amdgcn_global_load_lds(                                            \
      (const __attribute__((address_space(1))) void*)(gsrc),                   \
      (__attribute__((address_space(3))) void*)(ldst), 16, 0, 0)

// ---------------------------------------------------------------------------
// prep: rel f32(4095,64) -> bf16(4096,64) (row 4095 = dup of 4094, never used)
//       mbias[b*2048+t] = (1 - mask) * -1e9
// ---------------------------------------------------------------------------
__global__ void prep_kernel(const float* __restrict__ rel,
                            const float* __restrict__ mask,
                            bf16_t* __restrict__ relb,
                            float* __restrict__ mbias) {
  int idx = blockIdx.x * 256 + threadIdx.x;
  if (idx < 4096 * 64) {
    int row = idx >> 6;
    int col = idx & 63;
    int sr = row > 4094 ? 4094 : row;
    relb[idx] = (bf16_t)rel[sr * 64 + col];
  } else {
    int j = idx - 4096 * 64;
    if (j < 4096) mbias[j] = (1.0f - mask[j]) * -1e9f;
  }
}

// ---------------------------------------------------------------------------
// Fused projection GEMM: z in {0,1,2} picks (Q,WQ,qb),(K,WK,kb),(V,WV,vb).
// C[bt, h*64+p] = scale * sum_d A[bt,d] * W[h,d,p];  scale=1/8 for q.
// ---------------------------------------------------------------------------
__global__ __launch_bounds__(256) void proj_gemm_kernel(
    const float* __restrict__ Q, const float* __restrict__ K,
    const float* __restrict__ V, const float* __restrict__ WQ,
    const float* __restrict__ WK, const float* __restrict__ WV,
    bf16_t* __restrict__ qb, bf16_t* __restrict__ kb,
    bf16_t* __restrict__ vb) {
  const int z = blockIdx.z;
  const float* A = z == 0 ? Q : (z == 1 ? K : V);
  const float* W = z == 0 ? WQ : (z == 1 ? WK : WV);
  bf16_t* out = z == 0 ? qb : (z == 1 ? kb : vb);
  const float scale = z == 0 ? 0.125f : 1.0f;

  __shared__ bf16_t As[128][72];
  __shared__ bf16_t Bs[128][72];
  const int tid = threadIdx.x;
  const int lane = tid & 63;
  const int wid = tid >> 6;
  const int wm = wid >> 1, wn = wid & 1;
  const int row0 = blockIdx.x * 128;
  const int col0 = blockIdx.y * 128;
  const int lr = lane & 15;
  const int lk = (lane >> 4) * 8;

  f32x4 acc[4][4];
#pragma unroll
  for (int m = 0; m < 4; m++)
#pragma unroll
    for (int n = 0; n < 4; n++) acc[m][n] = {0.f, 0.f, 0.f, 0.f};

  for (int kt = 0; kt < 1024; kt += 64) {
#pragma unroll
    for (int i = 0; i < 4; i++) {
      int c = tid + i * 256;
      int row = c >> 3;
      int k8 = (c & 7) * 8;
      const float* src = A + (size_t)(row0 + row) * 1024 + kt + k8;
      bf16_t* dst = &As[row][k8];
#pragma unroll
      for (int j = 0; j < 8; j++) dst[j] = (bf16_t)src[j];
    }
#pragma unroll
    for (int i = 0; i < 4; i++) {
      int c = tid + i * 256;
      int col = c & 127;
      int k8 = (c >> 7) * 8;
      int gcol = col0 + col;
      int h = gcol >> 6, p = gcol & 63;
      const float* src = W + (size_t)h * 65536 + (size_t)(kt + k8) * 64 + p;
      bf16_t* dst = &Bs[col][k8];
#pragma unroll
      for (int j = 0; j < 8; j++) dst[j] = (bf16_t)src[j * 64];
    }
    __syncthreads();
#pragma unroll
    for (int kk = 0; kk < 2; kk++) {
      bf16x8 af[4], bfr[4];
#pragma unroll
      for (int m = 0; m < 4; m++)
        af[m] = *(const bf16x8*)&As[wm * 64 + m * 16 + lr][kk * 32 + lk];
#pragma unroll
      for (int n = 0; n < 4; n++)
        bfr[n] = *(const bf16x8*)&Bs[wn * 64 + n * 16 + lr][kk * 32 + lk];
#pragma unroll
      for (int m = 0; m < 4; m++)
#pragma unroll
        for (int n = 0; n < 4; n++)
          acc[m][n] = mfma16(af[m], bfr[n], acc[m][n]);
    }
    __syncthreads();
  }
  const int rb = (lane >> 4) * 4;
#pragma unroll
  for (int m = 0; m < 4; m++) {
#pragma unroll
    for (int n = 0; n < 4; n++) {
      int col = col0 + wn * 64 + n * 16 + lr;
      int h = col >> 6, p = col & 63;
#pragma unroll
      for (int r = 0; r < 4; r++) {
        int row = row0 + wm * 64 + m * 16 + rb + r;
        int b = row >> 11, tt = row & 2047;
        out[(((size_t)(b * 16 + h) * 2048 + tt) * 64) + p] =
            (bf16_t)(acc[m][n][r] * scale);
      }
    }
  }
}

// ---------------------------------------------------------------------------
// Dense output GEMM (unchanged): out = ctx(bf16) @ W(f32) + bias
// ---------------------------------------------------------------------------
__global__ __launch_bounds__(256) void dense_gemm_kernel(
    const bf16_t* __restrict__ A, const float* __restrict__ W,
    const float* __restrict__ bias, float* __restrict__ out) {
  __shared__ bf16_t As[128][72];
  __shared__ bf16_t Bs[128][72];
  const int tid = threadIdx.x;
  const int lane = tid & 63;
  const int wid = tid >> 6;
  const int wm = wid >> 1, wn = wid & 1;
  const int row0 = blockIdx.x * 128;
  const int col0 = blockIdx.y * 128;
  const int lr = lane & 15;
  const int lk = (lane >> 4) * 8;

  f32x4 acc[4][4];
#pragma unroll
  for (int m = 0; m < 4; m++)
#pragma unroll
    for (int n = 0; n < 4; n++) acc[m][n] = {0.f, 0.f, 0.f, 0.f};

  for (int kt = 0; kt < 1024; kt += 64) {
#pragma unroll
    for (int i = 0; i < 4; i++) {
      int c = tid + i * 256;
      int row = c >> 3;
      int k8 = (c & 7) * 8;
      *(uint4*)&As[row][k8] =
          *(const uint4*)(A + (size_t)(row0 + row) * 1024 + kt + k8);
    }
#pragma unroll
    for (int i = 0; i < 4; i++) {
      int c = tid + i * 256;
      int col = c & 127;
      int k8 = (c >> 7) * 8;
      const float* src = W + (size_t)(kt + k8) * 1024 + col0 + col;
      bf16_t* dst = &Bs[col][k8];
#pragma unroll
      for (int j = 0; j < 8; j++) dst[j] = (bf16_t)src[j * 1024];
    }
    __syncthreads();
#pragma unroll
    for (int kk = 0; kk < 2; kk++) {
      bf16x8 af[4], bfr[4];
#pragma unroll
      for (int m = 0; m < 4; m++)
        af[m] = *(const bf16x8*)&As[wm * 64 + m * 16 + lr][kk * 32 + lk];
#pragma unroll
      for (int n = 0; n < 4; n++)
        bfr[n] = *(const bf16x8*)&Bs[wn * 64 + n * 16 + lr][kk * 32 + lk];
#pragma unroll
      for (int m = 0; m < 4; m++)
#pragma unroll
        for (int n = 0; n < 4; n++)
          acc[m][n] = mfma16(af[m], bfr[n], acc[m][n]);
    }
    __syncthreads();
  }
  const int rb = (lane >> 4) * 4;
#pragma unroll
  for (int m = 0; m < 4; m++) {
#pragma unroll
    for (int n = 0; n < 4; n++) {
      int col = col0 + wn * 64 + n * 16 + lr;
      float bv = bias[col];
#pragma unroll
      for (int r = 0; r < 4; r++) {
        int row = row0 + wm * 64 + m * 16 + rb + r;
        out[(size_t)row * 1024 + col] = acc[m][n][r] + bv;
      }
    }
  }
}

// ---------------------------------------------------------------------------
// Flash attention with Shaw rel-pos bias.  q pre-scaled by 1/8.
// Linear LDS tiles with XOR swizzle col ^= (row&7)<<3 (elems); K/R staged via
// pre-swizzled-source global_load_lds; V transposed via reg->b128 write.
// Per-wave rel band: wave w needs bias cols [48-16w, 126-16w] -> 5 frags.
// EL/PL are per-wave: no barrier between spill and consume.
// ---------------------------------------------------------------------------
__global__ __launch_bounds__(256, 3) void attn_kernel(
    const bf16_t* __restrict__ qg, const bf16_t* __restrict__ kg,
    const bf16_t* __restrict__ vg, const bf16_t* __restrict__ relb,
    const float* __restrict__ mbias, bf16_t* __restrict__ ctx) {
  __shared__ bf16_t Kt[64 * 64];     // swizzled [j][p]        8 KB
  __shared__ bf16_t Vt[64 * 64];     // swizzled [p][j]        8 KB
  __shared__ bf16_t Rt[128 * 64];    // swizzled [r'][p]      16 KB
  __shared__ bf16_t EL[4][16 * 84];  // per-wave bias band  10.5 KB
  __shared__ bf16_t PL[4][16 * 64];  // per-wave P tile        8 KB

  const int tid = threadIdx.x;
  const int lane = tid & 63;
  const int w = tid >> 6;
  const int i0 = blockIdx.x * 64;
  const int h = blockIdx.y;
  const int b = blockIdx.z;
  const size_t base = ((size_t)(b * 16 + h)) * 2048 * 64;
  const int lr = lane & 15;
  const int g = lane >> 4;
  const int lk = g * 8;
  const int rloc = g * 4;
  const int nbase = 3 - w;   // wave's rel-band start frag
  const int srow = lane >> 3;  // staging row-within-chunk
  const int t16 = lane & 7;    // staging 16B slot

  bf16x8 aq[2];
  {
    const bf16_t* src = qg + base + (size_t)(i0 + w * 16 + lr) * 64 + lk;
    aq[0] = *(const bf16x8*)(src);
    aq[1] = *(const bf16x8*)(src + 32);
  }

  float mrow[4], lrow[4];
  f32x4 o[4];
#pragma unroll
  for (int r = 0; r < 4; r++) { mrow[r] = -INFINITY; lrow[r] = 0.f; }
#pragma unroll
  for (int n = 0; n < 4; n++) o[n] = {0.f, 0.f, 0.f, 0.f};

  const float* mb_base = mbias + (size_t)b * 2048;

  for (int jt = 0; jt < 32; jt++) {
    const int j0 = jt * 64;
    __syncthreads();  // all waves done reading prev K/V/R tiles
    // ---- stage K (8 KB): global_load_lds, source pre-swizzled
    {
      const bf16_t* kb = kg + base + (size_t)j0 * 64;
#pragma unroll
      for (int i = 0; i < 2; i++) {
        int chunk = i * 4 + w;
        int row = chunk * 8 + srow;
        GLDS16(kb + row * 64 + ((t16 ^ (row & 7)) * 8),
               Kt + chunk * 512 + lane * 8);
      }
    }
    // ---- stage R band (16 KB): rows rbase..rbase+127, always in [0,4095]
    {
      const bf16_t* rb = relb + (size_t)(j0 - i0 + 1984) * 64;
#pragma unroll
      for (int i = 0; i < 4; i++) {
        int chunk = i * 4 + w;
        int row = chunk * 8 + srow;
        GLDS16(rb + row * 64 + ((t16 ^ (row & 7)) * 8),
               Rt + chunk * 512 + lane * 8);
      }
    }
    // ---- stage V transposed (8 KB): coalesced loads -> swizzled b128 write
#pragma unroll
    for (int i = 0; i < 2; i++) {
      int j8 = (w + i * 4) * 8;
      const bf16_t* vs = vg + base + (size_t)(j0 + j8) * 64 + lane;
      bf16x8 pk;
#pragma unroll
      for (int jj = 0; jj < 8; jj++) pk[jj] = vs[jj * 64];
      *(bf16x8*)&Vt[lane * 64 + (j8 ^ ((lane & 7) << 3))] = pk;
    }
    __syncthreads();  // staging complete (vmcnt drained at barrier)

    // ---- QK^T and rel-band matmuls
    f32x4 sacc[4], er[5];
#pragma unroll
    for (int n = 0; n < 4; n++) sacc[n] = {0.f, 0.f, 0.f, 0.f};
#pragma unroll
    for (int n = 0; n < 5; n++) er[n] = {0.f, 0.f, 0.f, 0.f};
#pragma unroll
    for (int kk = 0; kk < 2; kk++) {
      int cb = kk * 32 + lk;
#pragma unroll
      for (int n = 0; n < 4; n++) {
        int row = n * 16 + lr;
        bf16x8 bk = *(const bf16x8*)&Kt[row * 64 + (cb ^ ((row & 7) << 3))];
        sacc[n] = mfma16(aq[kk], bk, sacc[n]);
      }
#pragma unroll
      for (int n2 = 0; n2 < 5; n2++) {
        int row = (nbase + n2) * 16 + lr;
        bf16x8 br = *(const bf16x8*)&Rt[row * 64 + (cb ^ ((row & 7) << 3))];
        er[n2] = mfma16(aq[kk], br, er[n2]);
      }
    }
    // ---- spill rel band (per-wave; DS in-order, no barrier)
#pragma unroll
    for (int n2 = 0; n2 < 5; n2++)
#pragma unroll
      for (int r = 0; r < 4; r++)
        EL[w][(rloc + r) * 84 + n2 * 16 + lr] = (bf16_t)er[n2][r];

    // ---- energies = sacc + bias_gather + mask-bias  (scale pre-folded)
    float stot[4][4];
#pragma unroll
    for (int n = 0; n < 4; n++) {
      int dj = n * 16 + lr;
      float mb = mb_base[j0 + dj];
#pragma unroll
      for (int r = 0; r < 4; r++)
        stot[n][r] =
            sacc[n][r] + (float)EL[w][(rloc + r) * 84 + (dj - rloc - r + 15)] +
            mb;
    }
    // ---- online softmax (rows live across 16 lanes of each group)
#pragma unroll
    for (int r = 0; r < 4; r++) {
      float v4 = fmaxf(fmaxf(stot[0][r], stot[1][r]),
                       fmaxf(stot[2][r], stot[3][r]));
#pragma unroll
      for (int xm = 1; xm < 16; xm <<= 1) v4 = fmaxf(v4, __shfl_xor(v4, xm, 64));
      float mnew = fmaxf(mrow[r], v4);
      float fac = exp2f((mrow[r] - mnew) * LOG2E);
      mrow[r] = mnew;
      float ps = 0.f;
#pragma unroll
      for (int n = 0; n < 4; n++) {
        stot[n][r] = exp2f((stot[n][r] - mnew) * LOG2E);
        ps += stot[n][r];
      }
#pragma unroll
      for (int xm = 1; xm < 16; xm <<= 1) ps += __shfl_xor(ps, xm, 64);
      lrow[r] = lrow[r] * fac + ps;
#pragma unroll
      for (int n = 0; n < 4; n++) o[n][r] *= fac;
    }
    // ---- P tile -> per-wave LDS (swizzled)
#pragma unroll
    for (int n = 0; n < 4; n++)
#pragma unroll
      for (int r = 0; r < 4; r++) {
        int row = rloc + r;
        PL[w][row * 64 + ((n * 16 + lr) ^ ((row & 7) << 3))] =
            (bf16_t)stot[n][r];
      }
    // ---- PV
#pragma unroll
    for (int kk = 0; kk < 2; kk++) {
      int cb = kk * 32 + lk;
      bf16x8 ap = *(const bf16x8*)&PL[w][lr * 64 + (cb ^ ((lr & 7) << 3))];
#pragma unroll
      for (int n = 0; n < 4; n++) {
        int row = n * 16 + lr;
        bf16x8 bv = *(const bf16x8*)&Vt[row * 64 + (cb ^ ((row & 7) << 3))];
        o[n] = mfma16(ap, bv, o[n]);
      }
    }
  }

  // ---- write ctx (bt, h*64+p) bf16
#pragma unroll
  for (int n = 0; n < 4; n++) {
    int p = n * 16 + lr;
#pragma unroll
    for (int r = 0; r < 4; r++) {
      int row = i0 + w * 16 + rloc + r;
      int bt = b * 2048 + row;
      ctx[(size_t)bt * 1024 + h * 64 + p] = (bf16_t)(o[n][r] / lrow[r]);
    }
  }
}

// ---------------------------------------------------------------------------
extern "C" void kernel_launch(void* const* d_in, const int* in_sizes, int n_in,
                              void* d_out, int out_size, void* d_ws,
                              size_t ws_size, hipStream_t stream) {
  (void)in_sizes; (void)n_in; (void)out_size; (void)ws_size;
  const float* Q    = (const float*)d_in[0];
  const float* K    = (const float*)d_in[1];
  const float* V    = (const float*)d_in[2];
  const float* mask = (const float*)d_in[3];
  const float* WQ   = (const float*)d_in[4];
  const float* WK   = (const float*)d_in[5];
  const float* WV   = (const float*)d_in[6];
  const float* rel  = (const float*)d_in[7];
  const float* dW   = (const float*)d_in[8];
  const float* db   = (const float*)d_in[9];
  float* out = (float*)d_out;

  const size_t NQKV = (size_t)2 * 16 * 2048 * 64;  // 4,194,304 elems
  bf16_t* qb   = (bf16_t*)d_ws;
  bf16_t* kb   = qb + NQKV;
  bf16_t* vb   = kb + NQKV;
  bf16_t* ctxb = vb + NQKV;
  bf16_t* relb = ctxb + NQKV;            // 4096*64 bf16
  float*  mbias = (float*)(relb + 4096 * 64);  // 4096 f32

  dim3 blk(256);
  prep_kernel<<<dim3((4096 * 64 + 4096) / 256), blk, 0, stream>>>(rel, mask,
                                                                  relb, mbias);
  proj_gemm_kernel<<<dim3(32, 8, 3), blk, 0, stream>>>(Q, K, V, WQ, WK, WV, qb,
                                                       kb, vb);
  attn_kernel<<<dim3(32, 16, 2), blk, 0, stream>>>(qb, kb, vb, relb, mbias,
                                                   ctxb);
  dense_gemm_kernel<<<dim3(32, 8), blk, 0, stream>>>(ctxb, dW, db, out);
}

// Round 3
// 244.372 us; speedup vs baseline: 1.5306x; 1.3375x over previous
//
#include <hip/hip_runtime.h>
#include <hip/hip_bf16.h>

typedef __bf16 bf16_t;
typedef __bf16 bf16x8 __attribute__((ext_vector_type(8)));
typedef float f32x4 __attribute__((ext_vector_type(4)));

#define QSCALE 0.1803368801111396f   /* 0.125 * log2(e) */
#define MLOG2E 1.4426950408889634f

__device__ __forceinline__ f32x4 mfma16(bf16x8 a, bf16x8 b, f32x4 c) {
  return __builtin_amdgcn_mfma_f32_16x16x32_bf16(a, b, c, 0, 0, 0);
}

#define GLDS16(gsrc, ldst)                                                     \
  __builtin_amdgcn_global_load_lds(                                            \
      (const __attribute__((address_space(1))) void*)(gsrc),                   \
      (__attribute__((address_space(3))) void*)(ldst), 16, 0, 0)

__device__ __forceinline__ unsigned short bhalf(float f) {
  return __builtin_bit_cast(unsigned short, (bf16_t)f);
}

// ---------------------------------------------------------------------------
// prep: rel f32(4095,64) -> bf16(4096,64) (row 4095 dup, staged-never-used)
//       mbias[b*2048+t] = (1 - mask) * -1e9 * log2e
// ---------------------------------------------------------------------------
__global__ void prep_kernel(const float* __restrict__ rel,
                            const float* __restrict__ mask,
                            bf16_t* __restrict__ relb,
                            float* __restrict__ mbias) {
  int idx = blockIdx.x * 256 + threadIdx.x;
  if (idx < 4096 * 64) {
    int row = idx >> 6;
    int col = idx & 63;
    int sr = row > 4094 ? 4094 : row;
    relb[idx] = (bf16_t)rel[sr * 64 + col];
  } else {
    int j = idx - 4096 * 64;
    if (j < 4096) mbias[j] = (1.0f - mask[j]) * -1e9f * MLOG2E;
  }
}

// ---------------------------------------------------------------------------
// Fused projection GEMM: z=0 -> qb scaled by 0.125*log2e, (b,h,t,p) layout.
// z=1 -> kb (b,h,t,p).  z=2 -> vb TRANSPOSED (b,h,p,t).
// ---------------------------------------------------------------------------
__global__ __launch_bounds__(256) void proj_gemm_kernel(
    const float* __restrict__ Q, const float* __restrict__ K,
    const float* __restrict__ V, const float* __restrict__ WQ,
    const float* __restrict__ WK, const float* __restrict__ WV,
    bf16_t* __restrict__ qb, bf16_t* __restrict__ kb,
    bf16_t* __restrict__ vb) {
  const int z = blockIdx.z;
  const float* A = z == 0 ? Q : (z == 1 ? K : V);
  const float* W = z == 0 ? WQ : (z == 1 ? WK : WV);
  bf16_t* out = z == 0 ? qb : (z == 1 ? kb : vb);
  const float scale = z == 0 ? QSCALE : 1.0f;

  __shared__ bf16_t As[128][72];
  __shared__ bf16_t Bs[128][72];
  const int tid = threadIdx.x;
  const int lane = tid & 63;
  const int wid = tid >> 6;
  const int wm = wid >> 1, wn = wid & 1;
  const int row0 = blockIdx.x * 128;
  const int col0 = blockIdx.y * 128;
  const int lr = lane & 15;
  const int lk = (lane >> 4) * 8;

  f32x4 acc[4][4];
#pragma unroll
  for (int m = 0; m < 4; m++)
#pragma unroll
    for (int n = 0; n < 4; n++) acc[m][n] = {0.f, 0.f, 0.f, 0.f};

  for (int kt = 0; kt < 1024; kt += 64) {
#pragma unroll
    for (int i = 0; i < 4; i++) {
      int c = tid + i * 256;
      int row = c >> 3;
      int k8 = (c & 7) * 8;
      const float* src = A + (size_t)(row0 + row) * 1024 + kt + k8;
      bf16_t* dst = &As[row][k8];
#pragma unroll
      for (int j = 0; j < 8; j++) dst[j] = (bf16_t)src[j];
    }
#pragma unroll
    for (int i = 0; i < 4; i++) {
      int c = tid + i * 256;
      int col = c & 127;
      int k8 = (c >> 7) * 8;
      int gcol = col0 + col;
      int h = gcol >> 6, p = gcol & 63;
      const float* src = W + (size_t)h * 65536 + (size_t)(kt + k8) * 64 + p;
      bf16_t* dst = &Bs[col][k8];
#pragma unroll
      for (int j = 0; j < 8; j++) dst[j] = (bf16_t)src[j * 64];
    }
    __syncthreads();
#pragma unroll
    for (int kk = 0; kk < 2; kk++) {
      bf16x8 af[4], bfr[4];
#pragma unroll
      for (int m = 0; m < 4; m++)
        af[m] = *(const bf16x8*)&As[wm * 64 + m * 16 + lr][kk * 32 + lk];
#pragma unroll
      for (int n = 0; n < 4; n++)
        bfr[n] = *(const bf16x8*)&Bs[wn * 64 + n * 16 + lr][kk * 32 + lk];
#pragma unroll
      for (int m = 0; m < 4; m++)
#pragma unroll
        for (int n = 0; n < 4; n++)
          acc[m][n] = mfma16(af[m], bfr[n], acc[m][n]);
    }
    __syncthreads();
  }
  const int rb = (lane >> 4) * 4;
#pragma unroll
  for (int m = 0; m < 4; m++) {
#pragma unroll
    for (int n = 0; n < 4; n++) {
      int col = col0 + wn * 64 + n * 16 + lr;
      int h = col >> 6, p = col & 63;
      int row_base = row0 + wm * 64 + m * 16 + rb;
      int b = row_base >> 11, t0 = row_base & 2047;
      if (z == 2) {
        // transposed store: vb[((b*16+h)*64+p)*2048 + t], t contiguous over r
        unsigned u0 = ((unsigned)bhalf(acc[m][n][1]) << 16) | bhalf(acc[m][n][0]);
        unsigned u1 = ((unsigned)bhalf(acc[m][n][3]) << 16) | bhalf(acc[m][n][2]);
        uint2 u = {u0, u1};
        *(uint2*)&out[(((size_t)(b * 16 + h) * 64 + p) * 2048) + t0] = u;
      } else {
#pragma unroll
        for (int r = 0; r < 4; r++) {
          out[(((size_t)(b * 16 + h) * 2048 + t0 + r) * 64) + p] =
              (bf16_t)(acc[m][n][r] * scale);
        }
      }
    }
  }
}

// ---------------------------------------------------------------------------
// Dense output GEMM: out = ctx(bf16) @ W(f32) + bias
// ---------------------------------------------------------------------------
__global__ __launch_bounds__(256) void dense_gemm_kernel(
    const bf16_t* __restrict__ A, const float* __restrict__ W,
    const float* __restrict__ bias, float* __restrict__ out) {
  __shared__ bf16_t As[128][72];
  __shared__ bf16_t Bs[128][72];
  const int tid = threadIdx.x;
  const int lane = tid & 63;
  const int wid = tid >> 6;
  const int wm = wid >> 1, wn = wid & 1;
  const int row0 = blockIdx.x * 128;
  const int col0 = blockIdx.y * 128;
  const int lr = lane & 15;
  const int lk = (lane >> 4) * 8;

  f32x4 acc[4][4];
#pragma unroll
  for (int m = 0; m < 4; m++)
#pragma unroll
    for (int n = 0; n < 4; n++) acc[m][n] = {0.f, 0.f, 0.f, 0.f};

  for (int kt = 0; kt < 1024; kt += 64) {
#pragma unroll
    for (int i = 0; i < 4; i++) {
      int c = tid + i * 256;
      int row = c >> 3;
      int k8 = (c & 7) * 8;
      *(uint4*)&As[row][k8] =
          *(const uint4*)(A + (size_t)(row0 + row) * 1024 + kt + k8);
    }
#pragma unroll
    for (int i = 0; i < 4; i++) {
      int c = tid + i * 256;
      int col = c & 127;
      int k8 = (c >> 7) * 8;
      const float* src = W + (size_t)(kt + k8) * 1024 + col0 + col;
      bf16_t* dst = &Bs[col][k8];
#pragma unroll
      for (int j = 0; j < 8; j++) dst[j] = (bf16_t)src[j * 1024];
    }
    __syncthreads();
#pragma unroll
    for (int kk = 0; kk < 2; kk++) {
      bf16x8 af[4], bfr[4];
#pragma unroll
      for (int m = 0; m < 4; m++)
        af[m] = *(const bf16x8*)&As[wm * 64 + m * 16 + lr][kk * 32 + lk];
#pragma unroll
      for (int n = 0; n < 4; n++)
        bfr[n] = *(const bf16x8*)&Bs[wn * 64 + n * 16 + lr][kk * 32 + lk];
#pragma unroll
      for (int m = 0; m < 4; m++)
#pragma unroll
        for (int n = 0; n < 4; n++)
          acc[m][n] = mfma16(af[m], bfr[n], acc[m][n]);
    }
    __syncthreads();
  }
  const int rb = (lane >> 4) * 4;
#pragma unroll
  for (int m = 0; m < 4; m++) {
#pragma unroll
    for (int n = 0; n < 4; n++) {
      int col = col0 + wn * 64 + n * 16 + lr;
      float bv = bias[col];
#pragma unroll
      for (int r = 0; r < 4; r++) {
        int row = row0 + wm * 64 + m * 16 + rb + r;
        out[(size_t)row * 1024 + col] = acc[m][n][r] + bv;
      }
    }
  }
}

// ---------------------------------------------------------------------------
// Flash attention, swapped-operand layout (S^T, Er^T, ctx^T).
// q pre-scaled by 0.125*log2e.  vb is V^T (b,h,p,t).  Each lane owns one
// query column (lr) and 16 keys -> in-lane softmax, 2 shfls per reduce.
// ---------------------------------------------------------------------------
__global__ __launch_bounds__(256, 3) void attn_kernel(
    const bf16_t* __restrict__ qg, const bf16_t* __restrict__ kg,
    const bf16_t* __restrict__ vt, const bf16_t* __restrict__ relb,
    const float* __restrict__ mbias, bf16_t* __restrict__ ctx) {
  __shared__ bf16_t Kt[64 * 64];      // swizzled [key][d]      8 KB
  __shared__ bf16_t Vt[64 * 64];      // swizzled [p][key]      8 KB
  __shared__ bf16_t Rt[128 * 64];     // swizzled [r'][d]      16 KB
  __shared__ unsigned EL[4][16 * 41]; // per-wave bias band  10.25 KB
  __shared__ bf16_t PL[4][16 * 64];   // per-wave P^T tile      8 KB

  const int tid = threadIdx.x;
  const int lane = tid & 63;
  const int w = tid >> 6;
  const int i0 = blockIdx.x * 64;
  const int h = blockIdx.y;
  const int b = blockIdx.z;
  const size_t base = ((size_t)(b * 16 + h)) * 2048 * 64;
  const int lr = lane & 15;
  const int g = lane >> 4;
  const int lk = g * 8;
  const int nbase = 3 - w;     // wave's rel-band start frag
  const int srow = lane >> 3;  // staging row-within-chunk
  const int t16 = lane & 7;    // staging 16B slot
  const int swz = (lr & 7) << 3;

  bf16x8 aq[2];
  {
    const bf16_t* src = qg + base + (size_t)(i0 + w * 16 + lr) * 64 + lk;
    aq[0] = *(const bf16x8*)(src);
    aq[1] = *(const bf16x8*)(src + 32);
  }

  float m = -INFINITY, l = 0.f;
  f32x4 o[4];
#pragma unroll
  for (int n = 0; n < 4; n++) o[n] = {0.f, 0.f, 0.f, 0.f};

  const float* mb_base = mbias + (size_t)b * 2048;

  for (int jt = 0; jt < 32; jt++) {
    const int j0 = jt * 64;
    __syncthreads();  // all waves done reading prev tiles
    // ---- stage K (8 KB)
    {
      const bf16_t* kb = kg + base + (size_t)j0 * 64;
#pragma unroll
      for (int i = 0; i < 2; i++) {
        int chunk = i * 4 + w;
        int row = chunk * 8 + srow;
        GLDS16(kb + row * 64 + ((t16 ^ (row & 7)) * 8),
               Kt + chunk * 512 + lane * 8);
      }
    }
    // ---- stage R band (16 KB): rows j0-i0+1984 .. +127, within [0,4095]
    {
      const bf16_t* rb = relb + (size_t)(j0 - i0 + 1984) * 64;
#pragma unroll
      for (int i = 0; i < 4; i++) {
        int chunk = i * 4 + w;
        int row = chunk * 8 + srow;
        GLDS16(rb + row * 64 + ((t16 ^ (row & 7)) * 8),
               Rt + chunk * 512 + lane * 8);
      }
    }
    // ---- stage V^T (8 KB): rows p, cols keys (coalesced from global V^T)
    {
      const bf16_t* vs = vt + base + j0;
#pragma unroll
      for (int i = 0; i < 2; i++) {
        int chunk = i * 4 + w;
        int p = chunk * 8 + srow;
        GLDS16(vs + (size_t)p * 2048 + ((t16 ^ (p & 7)) * 8),
               Vt + chunk * 512 + lane * 8);
      }
    }
    __syncthreads();  // staging complete

    // ---- S^T = K q^T ; Er^T = R q^T
    f32x4 sacc[4], er[5];
#pragma unroll
    for (int n = 0; n < 4; n++) sacc[n] = {0.f, 0.f, 0.f, 0.f};
#pragma unroll
    for (int n = 0; n < 5; n++) er[n] = {0.f, 0.f, 0.f, 0.f};
    __builtin_amdgcn_s_setprio(1);
#pragma unroll
    for (int kk = 0; kk < 2; kk++) {
      int cbs = (kk * 32 + lk) ^ swz;
#pragma unroll
      for (int n = 0; n < 4; n++) {
        bf16x8 ak = *(const bf16x8*)&Kt[(n * 16 + lr) * 64 + cbs];
        sacc[n] = mfma16(ak, aq[kk], sacc[n]);
      }
#pragma unroll
      for (int n2 = 0; n2 < 5; n2++) {
        bf16x8 ar = *(const bf16x8*)&Rt[((nbase + n2) * 16 + lr) * 64 + cbs];
        er[n2] = mfma16(ar, aq[kk], er[n2]);
      }
    }
    __builtin_amdgcn_s_setprio(0);
    // ---- spill rel band (per-wave, uint-typed; rloc = n2*16+g*4+reg)
#pragma unroll
    for (int n2 = 0; n2 < 5; n2++) {
      EL[w][lr * 41 + n2 * 8 + g * 2 + 0] =
          ((unsigned)bhalf(er[n2][1]) << 16) | bhalf(er[n2][0]);
      EL[w][lr * 41 + n2 * 8 + g * 2 + 1] =
          ((unsigned)bhalf(er[n2][3]) << 16) | bhalf(er[n2][2]);
    }

    // ---- energies: s[key] = sacc + bias[key-lr+15] + mbias[key]
    float s[4][4];
#pragma unroll
    for (int n = 0; n < 4; n++) {
      f32x4 mbv = *(const f32x4*)&mb_base[j0 + n * 16 + g * 4];
#pragma unroll
      for (int r = 0; r < 4; r++) {
        int key = n * 16 + g * 4 + r;
        int idx = key - lr + 15;  // in [0,78]
        unsigned d = EL[w][lr * 41 + (idx >> 1)];
        float bias = __builtin_bit_cast(float, (d >> ((idx & 1) << 4)) << 16);
        s[n][r] = sacc[n][r] + bias + mbv[r];
      }
    }
    // ---- in-lane softmax over 16 keys + 2-shfl cross-group reduce
    float a0 = fmaxf(fmaxf(s[0][0], s[0][1]), fmaxf(s[0][2], s[0][3]));
    float a1 = fmaxf(fmaxf(s[1][0], s[1][1]), fmaxf(s[1][2], s[1][3]));
    float a2 = fmaxf(fmaxf(s[2][0], s[2][1]), fmaxf(s[2][2], s[2][3]));
    float a3 = fmaxf(fmaxf(s[3][0], s[3][1]), fmaxf(s[3][2], s[3][3]));
    float pm = fmaxf(fmaxf(a0, a1), fmaxf(a2, a3));
    pm = fmaxf(pm, __shfl_xor(pm, 16, 64));
    pm = fmaxf(pm, __shfl_xor(pm, 32, 64));
    float mnew = fmaxf(m, pm);
    float fac = exp2f(m - mnew);
    m = mnew;
    float ps = 0.f;
#pragma unroll
    for (int n = 0; n < 4; n++) {
      float e0 = exp2f(s[n][0] - mnew);
      float e1 = exp2f(s[n][1] - mnew);
      float e2 = exp2f(s[n][2] - mnew);
      float e3 = exp2f(s[n][3] - mnew);
      s[n][0] = e0; s[n][1] = e1; s[n][2] = e2; s[n][3] = e3;
      ps += (e0 + e1) + (e2 + e3);
    }
    ps += __shfl_xor(ps, 16, 64);
    ps += __shfl_xor(ps, 32, 64);
    l = l * fac + ps;
#pragma unroll
    for (int n = 0; n < 4; n++) {
      o[n][0] *= fac; o[n][1] *= fac; o[n][2] *= fac; o[n][3] *= fac;
    }
    // ---- P^T -> per-wave LDS (swizzled; row = query = lr, col = key)
#pragma unroll
    for (int n = 0; n < 4; n++)
#pragma unroll
      for (int r = 0; r < 4; r++) {
        int key = n * 16 + g * 4 + r;
        PL[w][lr * 64 + (key ^ swz)] = (bf16_t)s[n][r];
      }
    // ---- ctx^T += V^T P : A = V^T (rows p), B = P^T (cols query)
    __builtin_amdgcn_s_setprio(1);
#pragma unroll
    for (int kk = 0; kk < 2; kk++) {
      int cb = kk * 32 + lk;
      int cbs = cb ^ swz;
      bf16x8 bp = *(const bf16x8*)&PL[w][lr * 64 + cbs];
#pragma unroll
      for (int n = 0; n < 4; n++) {
        bf16x8 av = *(const bf16x8*)&Vt[(n * 16 + lr) * 64 + cbs];
        o[n] = mfma16(av, bp, o[n]);
      }
    }
    __builtin_amdgcn_s_setprio(0);
  }

  // ---- write ctx (bt, h*64+p): o rows are p, col (=lr) is query
  float inv = 1.0f / l;
  size_t bt = (size_t)b * 2048 + i0 + w * 16 + lr;
#pragma unroll
  for (int n = 0; n < 4; n++) {
    unsigned u0 = ((unsigned)bhalf(o[n][1] * inv) << 16) | bhalf(o[n][0] * inv);
    unsigned u1 = ((unsigned)bhalf(o[n][3] * inv) << 16) | bhalf(o[n][2] * inv);
    uint2 u = {u0, u1};
    *(uint2*)&ctx[bt * 1024 + h * 64 + n * 16 + g * 4] = u;
  }
}

// ---------------------------------------------------------------------------
extern "C" void kernel_launch(void* const* d_in, const int* in_sizes, int n_in,
                              void* d_out, int out_size, void* d_ws,
                              size_t ws_size, hipStream_t stream) {
  (void)in_sizes; (void)n_in; (void)out_size; (void)ws_size;
  const float* Q    = (const float*)d_in[0];
  const float* K    = (const float*)d_in[1];
  const float* V    = (const float*)d_in[2];
  const float* mask = (const float*)d_in[3];
  const float* WQ   = (const float*)d_in[4];
  const float* WK   = (const float*)d_in[5];
  const float* WV   = (const float*)d_in[6];
  const float* rel  = (const float*)d_in[7];
  const float* dW   = (const float*)d_in[8];
  const float* db   = (const float*)d_in[9];
  float* out = (float*)d_out;

  const size_t NQKV = (size_t)2 * 16 * 2048 * 64;
  bf16_t* qb   = (bf16_t*)d_ws;
  bf16_t* kb   = qb + NQKV;
  bf16_t* vb   = kb + NQKV;   // holds V^T (b,h,p,t)
  bf16_t* ctxb = vb + NQKV;
  bf16_t* relb = ctxb + NQKV;                  // 4096*64 bf16
  float*  mbias = (float*)(relb + 4096 * 64);  // 4096 f32

  dim3 blk(256);
  prep_kernel<<<dim3((4096 * 64 + 4096) / 256), blk, 0, stream>>>(rel, mask,
                                                                  relb, mbias);
  proj_gemm_kernel<<<dim3(32, 8, 3), blk, 0, stream>>>(Q, K, V, WQ, WK, WV, qb,
                                                       kb, vb);
  attn_kernel<<<dim3(32, 16, 2), blk, 0, stream>>>(qb, kb, vb, relb, mbias,
                                                   ctxb);
  dense_gemm_kernel<<<dim3(32, 8), blk, 0, stream>>>(ctxb, dW, db, out);
}